// Round 13
// baseline (271.008 us; speedup 1.0000x reference)
//
#include <hip/hip_runtime.h>
#include <hip/hip_bf16.h>
#include <math.h>

#define NB 32
#define NR 512
#define NT 128

typedef __attribute__((ext_vector_type(8))) short short8;
typedef __attribute__((ext_vector_type(4))) float f32x4;
typedef __attribute__((ext_vector_type(2))) float f32x2;

// ---------------- wave (64-lane) reductions ----------------
__device__ __forceinline__ float wred_max(float v){
#pragma unroll
  for (int o = 32; o > 0; o >>= 1) v = fmaxf(v, __shfl_xor(v, o));
  return v;
}
__device__ __forceinline__ float wred_sum(float v){
#pragma unroll
  for (int o = 32; o > 0; o >>= 1) v += __shfl_xor(v, o);
  return v;
}
__device__ __forceinline__ float dot4(float4 a, float4 b){
  return a.x * b.x + a.y * b.y + a.z * b.z + a.w * b.w;
}

// 16-lane-group sum via DPP row_shr (VALU-only, no LDS). Result in n16==15.
__device__ __forceinline__ float dpp_add16(float s){
  int x;
  x = __builtin_amdgcn_update_dpp(0, __float_as_int(s), 0x111, 0xf, 0xf, true);
  s += __int_as_float(x);   // row_shr:1
  x = __builtin_amdgcn_update_dpp(0, __float_as_int(s), 0x112, 0xf, 0xf, true);
  s += __int_as_float(x);   // row_shr:2
  x = __builtin_amdgcn_update_dpp(0, __float_as_int(s), 0x114, 0xf, 0xf, true);
  s += __int_as_float(x);   // row_shr:4
  x = __builtin_amdgcn_update_dpp(0, __float_as_int(s), 0x118, 0xf, 0xf, true);
  s += __int_as_float(x);   // row_shr:8
  return s;
}

// ---------------- encoder kernel v2 (R9-proven): 641 blocks x 256 thr ------
__global__ __launch_bounds__(256) void enc_kernel(
    const float* __restrict__ rs, const float* __restrict__ ts,
    const float* __restrict__ r_w1, const float* __restrict__ r_b1,
    const float* __restrict__ r_w2, const float* __restrict__ r_b2,
    const float* __restrict__ t_w1, const float* __restrict__ t_b1,
    const float* __restrict__ t_w2, const float* __restrict__ t_b2,
    const float* __restrict__ wq, const float* __restrict__ bq,
    const float* __restrict__ wk, const float* __restrict__ bk,
    const float* __restrict__ wv, const float* __restrict__ bv,
    const float* __restrict__ a_w1, const float* __restrict__ a_w2,
    float* __restrict__ kbuf, float* __restrict__ vbuf,
    float* __restrict__ rpbuf, float* __restrict__ qbuf,
    unsigned short* __restrict__ w2f)
{
  __shared__ float w1s[448];
  __shared__ float wss[4096];
  __shared__ float h_s[32 * 66];
  __shared__ float rf_s[32 * 66];

  const int tid = threadIdx.x;
  const int blk = blockIdx.x;

  if (blk == 640) {        // fused prep: split a_w2 into hi/lo bf16 B-frags
    if (tid < 64) {
      int l = tid, n16 = l & 15, g = l >> 4;
      for (int f = 0; f < 8; ++f) {
        int ntile = f & 1, ks = (f >> 1) & 1, part = f >> 2;
        for (int j = 0; j < 8; ++j) {
          int k = ks * 32 + g * 8 + j;
          int n = ntile * 16 + n16;
          unsigned wb = __float_as_uint(a_w2[k * 32 + n]);
          unsigned hib = wb & 0xffff0000u;
          float lof = __uint_as_float(wb) - __uint_as_float(hib);
          unsigned lob = __float_as_uint(lof) & 0xffff0000u;
          w2f[((size_t)f * 64 + l) * 8 + j] =
              (unsigned short)((part == 0 ? hib : lob) >> 16);
        }
      }
    }
    return;
  }

  const int rb = tid >> 3, t8 = tid & 7;
  const bool robot = blk < 512;

  if (robot) {
    if (tid < 112) ((float4*)w1s)[tid] = ((const float4*)r_w1)[tid];
#pragma unroll
    for (int c = 0; c < 4; ++c)
      ((float4*)wss)[c * 256 + tid] = ((const float4*)r_w2)[c * 256 + tid];
  } else {
    if (tid < 96) ((float4*)w1s)[tid] = ((const float4*)t_w1)[tid];
#pragma unroll
    for (int c = 0; c < 4; ++c)
      ((float4*)wss)[c * 256 + tid] = ((const float4*)t_w2)[c * 256 + tid];
  }

  int g, K1;
  const float* xin; const float* b1; const float* b2;
  if (robot) { g = blk * 32 + rb;          K1 = 7; xin = rs + (size_t)g * 7; b1 = r_b1; b2 = r_b2; }
  else       { g = (blk - 512) * 32 + rb;  K1 = 6; xin = ts + (size_t)g * 6; b1 = t_b1; b2 = t_b2; }

  float x[7];
  for (int k = 0; k < K1; ++k) x[k] = xin[k];
  __syncthreads();

  // stage 1: hidden = relu(x @ W1 + b1)
  {
    float acc[8];
#pragma unroll
    for (int jj = 0; jj < 8; ++jj) acc[jj] = b1[t8 * 8 + jj];
    for (int k = 0; k < K1; ++k) {
      float xv = x[k];
#pragma unroll
      for (int jj = 0; jj < 8; ++jj) acc[jj] += xv * w1s[k * 64 + t8 * 8 + jj];
    }
#pragma unroll
    for (int jj = 0; jj < 8; ++jj) h_s[rb * 66 + t8 * 8 + jj] = fmaxf(acc[jj], 0.f);
  }
  __syncthreads();

  // stage 2: rf = relu(hidden @ W2 + b2)
  {
    float acc[8];
#pragma unroll
    for (int jj = 0; jj < 8; ++jj) acc[jj] = b2[t8 * 8 + jj];
    for (int k = 0; k < 64; ++k) {
      float hv = h_s[rb * 66 + k];
      const float4* wr = (const float4*)(wss + k * 64 + t8 * 8);
#pragma unroll
      for (int j4 = 0; j4 < 2; ++j4) {
        float4 w = wr[j4];
        acc[j4 * 4 + 0] += hv * w.x; acc[j4 * 4 + 1] += hv * w.y;
        acc[j4 * 4 + 2] += hv * w.z; acc[j4 * 4 + 3] += hv * w.w;
      }
    }
#pragma unroll
    for (int jj = 0; jj < 8; ++jj) rf_s[rb * 66 + t8 * 8 + jj] = fmaxf(acc[jj], 0.f);
  }

  // stage 3: projection passes
  const float* wp[3]; const float* bp[3]; float* op[3]; int npass;
  if (robot) {
    wp[0] = wk; bp[0] = bk;      op[0] = kbuf;
    wp[1] = wv; bp[1] = bv;      op[1] = vbuf;
    wp[2] = a_w1 + 64 * 64; bp[2] = nullptr; op[2] = rpbuf;
    npass = 3;
  } else {
    wp[0] = wq; bp[0] = bq; op[0] = qbuf; npass = 1;
  }
  for (int p = 0; p < npass; ++p) {
    __syncthreads();
#pragma unroll
    for (int c = 0; c < 4; ++c)
      ((float4*)wss)[c * 256 + tid] = ((const float4*)wp[p])[c * 256 + tid];
    __syncthreads();
    float acc[8];
#pragma unroll
    for (int jj = 0; jj < 8; ++jj) acc[jj] = bp[p] ? bp[p][t8 * 8 + jj] : 0.f;
    for (int k = 0; k < 64; ++k) {
      float hv = rf_s[rb * 66 + k];
      const float4* wr = (const float4*)(wss + k * 64 + t8 * 8);
#pragma unroll
      for (int j4 = 0; j4 < 2; ++j4) {
        float4 w = wr[j4];
        acc[j4 * 4 + 0] += hv * w.x; acc[j4 * 4 + 1] += hv * w.y;
        acc[j4 * 4 + 2] += hv * w.z; acc[j4 * 4 + 3] += hv * w.w;
      }
    }
    float4* o4 = (float4*)(op[p] + (size_t)g * 64 + t8 * 8);
    o4[0] = make_float4(acc[0], acc[1], acc[2], acc[3]);
    o4[1] = make_float4(acc[4], acc[5], acc[6], acc[7]);
  }
}

// ---------------- split helpers (pair) -------------------------------------
__device__ __forceinline__ void mk2(f32x2 r, f32x2 t,
                                    unsigned* h, unsigned* l)
{
  f32x2 x = r + t;                                     // v_pk_add_f32
  x = __builtin_elementwise_max(x, (f32x2){0.f, 0.f}); // v_pk_max_f32
  __hip_bfloat162 hb = __float22bfloat162_rn(make_float2(x.x, x.y));
  unsigned hh; __builtin_memcpy(&hh, &hb, 4);
  f32x2 hf;
  hf.x = __int_as_float((int)(hh << 16));
  hf.y = __int_as_float((int)(hh & 0xffff0000u));
  f32x2 e = x - hf;                                    // exact residual
  __hip_bfloat162 lb = __float22bfloat162_rn(make_float2(e.x, e.y));
  unsigned ll; __builtin_memcpy(&ll, &lb, 4);
  *h = hh; *l = ll;
}

__device__ __forceinline__ void mk_frags(float4 ra, float4 rb,
                                         float4 ta, float4 tb,
                                         short8* Ah, short8* Al)
{
  unsigned h0, h1, h2, h3, l0, l1, l2, l3;
  mk2((f32x2){ra.x, ra.y}, (f32x2){ta.x, ta.y}, &h0, &l0);
  mk2((f32x2){ra.z, ra.w}, (f32x2){ta.z, ta.w}, &h1, &l1);
  mk2((f32x2){rb.x, rb.y}, (f32x2){tb.x, tb.y}, &h2, &l2);
  mk2((f32x2){rb.z, rb.w}, (f32x2){tb.z, tb.w}, &h3, &l3);
  *Ah = __builtin_bit_cast(short8, make_int4((int)h0, (int)h1, (int)h2, (int)h3));
  *Al = __builtin_bit_cast(short8, make_int4((int)l0, (int)l1, (int)l2, (int)l3));
}

// ---------------- fused attention + pairwise kernel ------------------------
// R11 body; launch_bounds(256,5): VGPR budget ~102 >= 64 actually used ->
// no spill (R10's (256,6) forced 40 and spilled), 5 blocks/CU vs 4.
#define LGS 520
__global__ __launch_bounds__(256, 5) void attn_pair_kernel(
    const float* __restrict__ qbuf, const float* __restrict__ kbuf,
    const float* __restrict__ vbuf,
    const float* __restrict__ wo, const float* __restrict__ bo,
    const float* __restrict__ a_w1, const float* __restrict__ a_b1,
    const unsigned short* __restrict__ w2f,
    const float* __restrict__ a_b2, const float* __restrict__ a_w3,
    const float* __restrict__ rpbuf,
    float* __restrict__ out)
{
  __shared__ float qt_s[2 * 64];        // q in phase A, tf in phase D
  __shared__ float lg[2][4 * LGS];      // logits/probs; reused for scores
  __shared__ float inv_s[8];
  __shared__ float cp[4][2 * 64];
  __shared__ float ctx_s[2 * 64];
  __shared__ float tp_f[2 * 64];
  __shared__ float red_a[4];
  __shared__ float red_b[4];

  float* const sc0 = &lg[0][0];         // scores task 0 (aliases lg, dead)
  float* const sc1 = &lg[1][0];         // scores task 1

  const int tid = threadIdx.x;
  const int jj = blockIdx.x & 31;
  const int b  = (jj & 7) * 4 + (jj >> 3);   // XCD-locality swizzle
  const int t0 = (blockIdx.x >> 5) * 2;      // 64 task-pairs

  // ---------- attn phase A: logits ----------
  if (tid < 32) {
    int tt = tid >> 4, i4 = tid & 15;
    float4 v = ((const float4*)(qbuf + (size_t)(b * NT + t0 + tt) * 64))[i4];
    v.x *= 0.25f; v.y *= 0.25f; v.z *= 0.25f; v.w *= 0.25f;   // 1/sqrt(16)
    ((float4*)qt_s)[tid] = v;
  }
  __syncthreads();

  {
    const int h = tid & 3;
    const int r0 = tid >> 2;
    const float4* q0 = (const float4*)(qt_s + h * 16);
    const float4* q1 = (const float4*)(qt_s + 64 + h * 16);
    float4 q0a = q0[0], q0b = q0[1], q0c = q0[2], q0d = q0[3];
    float4 q1a = q1[0], q1b = q1[1], q1c = q1[2], q1d = q1[3];
    const float* kb0 = kbuf + (size_t)b * NR * 64 + h * 16;
    for (int it = 0; it < 8; ++it) {
      int r = r0 + it * 64;
      const float4* k4 = (const float4*)(kb0 + (size_t)r * 64);
      float4 ka = k4[0], kb = k4[1], kc = k4[2], kd = k4[3];
      float s0 = dot4(q0a, ka) + dot4(q0b, kb) + dot4(q0c, kc) + dot4(q0d, kd);
      float s1 = dot4(q1a, ka) + dot4(q1b, kb) + dot4(q1c, kc) + dot4(q1d, kd);
      lg[0][h * LGS + r] = s0;
      lg[1][h * LGS + r] = s1;
    }
  }
  __syncthreads();

  // ---------- attn phase B: softmax ----------
  {
    int w = tid >> 6, lane = tid & 63;
    for (int p = 0; p < 2; ++p) {
      int pr = w * 2 + p, tt = pr >> 2, hh = pr & 3;
      float* row = &lg[tt][hh * LGS];
      float v0[8];
#pragma unroll
      for (int u = 0; u < 8; ++u) v0[u] = row[u * 64 + lane];
      float m = v0[0];
#pragma unroll
      for (int u = 1; u < 8; ++u) m = fmaxf(m, v0[u]);
      m = wred_max(m);
      float s = 0.f;
#pragma unroll
      for (int u = 0; u < 8; ++u) {
        float e = expf(v0[u] - m);
        row[u * 64 + lane] = e;
        s += e;
      }
      s = wred_sum(s);
      if (lane == 0) inv_s[tt * 4 + hh] = 1.f / s;
    }
  }
  __syncthreads();

  // ---------- attn phase C: ctx = p.v ----------
  {
    int od = tid & 63, ch = tid >> 6;
    int h = od >> 4, d = od & 15;
    float acc0 = 0.f, acc1 = 0.f;
    const float* vptr = vbuf + (size_t)b * NR * 64 + h * 16 + d;
#pragma unroll 4
    for (int u = 0; u < 128; ++u) {
      int r = ch * 128 + u;
      float vv = vptr[(size_t)r * 64];
      acc0 += lg[0][h * LGS + r] * vv;
      acc1 += lg[1][h * LGS + r] * vv;
    }
    cp[ch][od]      = acc0;
    cp[ch][64 + od] = acc1;
  }
  __syncthreads();
  if (tid < 128) {
    int od = tid & 63, h = od >> 4;
    ctx_s[tid] = (cp[0][tid] + cp[1][tid] + cp[2][tid] + cp[3][tid]) *
                 inv_s[(tid >> 6) * 4 + h];
  }
  __syncthreads();

  // ---------- attn phase D: tf = ctx @ wo + bo ----------
  {
    int jd = tid & 63, kc = tid >> 6;
    float p0 = 0.f, p1 = 0.f;
    for (int k = 0; k < 16; ++k) {
      float w = wo[(kc * 16 + k) * 64 + jd];
      p0 += ctx_s[kc * 16 + k] * w;
      p1 += ctx_s[64 + kc * 16 + k] * w;
    }
    cp[kc][jd]      = p0;
    cp[kc][64 + jd] = p1;
  }
  __syncthreads();
  if (tid < 128) {
    int jd = tid & 63;
    qt_s[tid] = cp[0][tid] + cp[1][tid] + cp[2][tid] + cp[3][tid] + bo[jd];
  }
  __syncthreads();

  // ---------- attn phase E: tp = tf @ a_w1[:64] + a_b1 -> LDS ----------
  {
    int jd = tid & 63, kc = tid >> 6;
    float p0 = 0.f, p1 = 0.f;
    for (int k = 0; k < 16; ++k) {
      float w = a_w1[(kc * 16 + k) * 64 + jd];
      p0 += qt_s[kc * 16 + k] * w;
      p1 += qt_s[64 + kc * 16 + k] * w;
    }
    cp[kc][jd]      = p0;
    cp[kc][64 + jd] = p1;
  }
  __syncthreads();
  if (tid < 128) {
    int jd = tid & 63;
    tp_f[tid] = cp[0][tid] + cp[1][tid] + cp[2][tid] + cp[3][tid] + a_b1[jd];
  }
  __syncthreads();

  // ---------- pair body ----------
  const int wave = tid >> 6, lane = tid & 63;
  const int n16 = lane & 15, g = lane >> 4;

  short8 B[8];
#pragma unroll
  for (int f = 0; f < 8; ++f)
    B[f] = __builtin_bit_cast(short8, ((const int4*)w2f)[f * 64 + lane]);

  const float* tpA = tp_f + g * 8;
  const float* tpB = tp_f + 64 + g * 8;
  float4 tA0a = *(const float4*)(tpA),      tA0b = *(const float4*)(tpA + 4);
  float4 tA1a = *(const float4*)(tpA + 32), tA1b = *(const float4*)(tpA + 36);
  float4 tB0a = *(const float4*)(tpB),      tB0b = *(const float4*)(tpB + 4);
  float4 tB1a = *(const float4*)(tpB + 32), tB1b = *(const float4*)(tpB + 36);

  float b20 = a_b2[n16], b21 = a_b2[16 + n16];
  float w30 = a_w3[n16], w31 = a_w3[16 + n16];

  const float* rpb = rpbuf + (size_t)b * NR * 64 + g * 8;

  const float4* rp0 = (const float4*)(rpb + (size_t)(wave * 128 + n16) * 64);
  float4 ra0 = rp0[0], rb0 = rp0[1], ra1 = rp0[8], rb1 = rp0[9];

#pragma unroll
  for (int mt = 0; mt < 8; ++mt) {
    float4 na0, nb0, na1, nb1;
    if (mt < 7) {
      const float4* rpn =
          (const float4*)(rpb + (size_t)(wave * 128 + (mt + 1) * 16 + n16) * 64);
      na0 = rpn[0]; nb0 = rpn[1]; na1 = rpn[8]; nb1 = rpn[9];
    }

#pragma unroll
    for (int task = 0; task < 2; ++task) {
      short8 Ah0, Al0, Ah1, Al1;
      if (task == 0) {
        mk_frags(ra0, rb0, tA0a, tA0b, &Ah0, &Al0);
        mk_frags(ra1, rb1, tA1a, tA1b, &Ah1, &Al1);
      } else {
        mk_frags(ra0, rb0, tB0a, tB0b, &Ah0, &Al0);
        mk_frags(ra1, rb1, tB1a, tB1b, &Ah1, &Al1);
      }
      f32x4 acc0 = (f32x4){b20, b20, b20, b20};
      f32x4 acc1 = (f32x4){b21, b21, b21, b21};
      acc0 = __builtin_amdgcn_mfma_f32_16x16x32_bf16(Ah0, B[0], acc0, 0, 0, 0);
      acc1 = __builtin_amdgcn_mfma_f32_16x16x32_bf16(Ah0, B[1], acc1, 0, 0, 0);
      acc0 = __builtin_amdgcn_mfma_f32_16x16x32_bf16(Al0, B[0], acc0, 0, 0, 0);
      acc1 = __builtin_amdgcn_mfma_f32_16x16x32_bf16(Al0, B[1], acc1, 0, 0, 0);
      acc0 = __builtin_amdgcn_mfma_f32_16x16x32_bf16(Ah0, B[4], acc0, 0, 0, 0);
      acc1 = __builtin_amdgcn_mfma_f32_16x16x32_bf16(Ah0, B[5], acc1, 0, 0, 0);
      acc0 = __builtin_amdgcn_mfma_f32_16x16x32_bf16(Ah1, B[2], acc0, 0, 0, 0);
      acc1 = __builtin_amdgcn_mfma_f32_16x16x32_bf16(Ah1, B[3], acc1, 0, 0, 0);
      acc0 = __builtin_amdgcn_mfma_f32_16x16x32_bf16(Al1, B[2], acc0, 0, 0, 0);
      acc1 = __builtin_amdgcn_mfma_f32_16x16x32_bf16(Al1, B[3], acc1, 0, 0, 0);
      acc0 = __builtin_amdgcn_mfma_f32_16x16x32_bf16(Ah1, B[6], acc0, 0, 0, 0);
      acc1 = __builtin_amdgcn_mfma_f32_16x16x32_bf16(Ah1, B[7], acc1, 0, 0, 0);
#pragma unroll
      for (int reg = 0; reg < 4; ++reg) {
        float s = fmaxf(acc0[reg], 0.f) * w30 + fmaxf(acc1[reg], 0.f) * w31;
        s = dpp_add16(s);                 // VALU-only 16-lane reduction
        if (n16 == 15) {
          float* scp = (task == 0) ? sc0 : sc1;
          scp[wave * 128 + mt * 16 + g * 4 + reg] = s;
        }
      }
    }
    ra0 = na0; rb0 = nb0; ra1 = na1; rb1 = nb1;
  }
  __syncthreads();

  // ---------- softmax over 512 robots, 2 tasks ----------
  const int lw = tid & 63, wid = tid >> 6;
  for (int task = 0; task < 2; ++task) {
    const float* scp = (task == 0) ? sc0 : sc1;
    float s0 = scp[tid], s1 = scp[tid + 256];
    float mw = wred_max(fmaxf(s0, s1));
    if (lw == 0) red_a[wid] = mw;
    __syncthreads();
    float m = fmaxf(fmaxf(red_a[0], red_a[1]), fmaxf(red_a[2], red_a[3]));
    float e0 = expf(s0 - m), e1 = expf(s1 - m);
    float sw = wred_sum(e0 + e1);
    if (lw == 0) red_b[wid] = sw;
    __syncthreads();
    float inv = 1.f / (red_b[0] + red_b[1] + red_b[2] + red_b[3]);
    float* op = out + (size_t)(b * NT + t0 + task) * NR;
    op[tid]       = e0 * inv;
    op[256 + tid] = e1 * inv;
  }
}

// ---------------- launch ----------------
extern "C" void kernel_launch(void* const* d_in, const int* in_sizes, int n_in,
                              void* d_out, int out_size, void* d_ws, size_t ws_size,
                              hipStream_t stream)
{
  const float* rs   = (const float*)d_in[0];
  const float* ts   = (const float*)d_in[1];
  const float* r_w1 = (const float*)d_in[2];  const float* r_b1 = (const float*)d_in[3];
  const float* r_w2 = (const float*)d_in[4];  const float* r_b2 = (const float*)d_in[5];
  const float* t_w1 = (const float*)d_in[6];  const float* t_b1 = (const float*)d_in[7];
  const float* t_w2 = (const float*)d_in[8];  const float* t_b2 = (const float*)d_in[9];
  const float* wq   = (const float*)d_in[10]; const float* bq   = (const float*)d_in[11];
  const float* wk   = (const float*)d_in[12]; const float* bk   = (const float*)d_in[13];
  const float* wv   = (const float*)d_in[14]; const float* bv   = (const float*)d_in[15];
  const float* wo   = (const float*)d_in[16]; const float* bo   = (const float*)d_in[17];
  const float* a_w1 = (const float*)d_in[18]; const float* a_b1 = (const float*)d_in[19];
  const float* a_w2 = (const float*)d_in[20]; const float* a_b2 = (const float*)d_in[21];
  const float* a_w3 = (const float*)d_in[22]; const float* a_b3 = (const float*)d_in[23];

  float* wsf   = (float*)d_ws;
  float* kbuf  = wsf;                                   // 32*512*64
  float* vbuf  = kbuf  + (size_t)NB * NR * 64;          // 32*512*64
  float* rpbuf = vbuf  + (size_t)NB * NR * 64;          // 32*512*64
  float* qbuf  = rpbuf + (size_t)NB * NR * 64;          // 32*128*64
  unsigned short* w2f = (unsigned short*)(qbuf + (size_t)NB * NT * 64); // 8*64*8

  enc_kernel<<<dim3(641), dim3(256), 0, stream>>>(
      rs, ts, r_w1, r_b1, r_w2, r_b2, t_w1, t_b1, t_w2, t_b2,
      wq, bq, wk, bk, wv, bv, a_w1, a_w2, kbuf, vbuf, rpbuf, qbuf, w2f);

  attn_pair_kernel<<<dim3(2048), dim3(256), 0, stream>>>(
      qbuf, kbuf, vbuf, wo, bo, a_w1, a_b1, w2f, a_b2, a_w3, rpbuf,
      (float*)d_out);
}

// Round 14
// 209.003 us; speedup vs baseline: 1.2967x; 1.2967x over previous
//
#include <hip/hip_runtime.h>
#include <hip/hip_bf16.h>
#include <math.h>

#define NB 32
#define NR 512
#define NT 128

typedef __attribute__((ext_vector_type(8))) short short8;
typedef __attribute__((ext_vector_type(4))) float f32x4;
typedef __attribute__((ext_vector_type(2))) float f32x2;

// ---------------- wave (64-lane) reductions ----------------
__device__ __forceinline__ float wred_max(float v){
#pragma unroll
  for (int o = 32; o > 0; o >>= 1) v = fmaxf(v, __shfl_xor(v, o));
  return v;
}
__device__ __forceinline__ float wred_sum(float v){
#pragma unroll
  for (int o = 32; o > 0; o >>= 1) v += __shfl_xor(v, o);
  return v;
}
__device__ __forceinline__ float dot4(float4 a, float4 b){
  return a.x * b.x + a.y * b.y + a.z * b.z + a.w * b.w;
}

// 16-lane-group sum via DPP row_shr (VALU-only, no LDS). Result in n16==15.
__device__ __forceinline__ float dpp_add16(float s){
  int x;
  x = __builtin_amdgcn_update_dpp(0, __float_as_int(s), 0x111, 0xf, 0xf, true);
  s += __int_as_float(x);   // row_shr:1
  x = __builtin_amdgcn_update_dpp(0, __float_as_int(s), 0x112, 0xf, 0xf, true);
  s += __int_as_float(x);   // row_shr:2
  x = __builtin_amdgcn_update_dpp(0, __float_as_int(s), 0x114, 0xf, 0xf, true);
  s += __int_as_float(x);   // row_shr:4
  x = __builtin_amdgcn_update_dpp(0, __float_as_int(s), 0x118, 0xf, 0xf, true);
  s += __int_as_float(x);   // row_shr:8
  return s;
}

// ---------------- encoder kernel v2 (R9-proven): 641 blocks x 256 thr ------
// NOTE: launch_bounds min-waves experiments on attn_pair: (256,4)->64 VGPR OK;
// (256,5)->48 VGPR SPILL (R13, FETCH 107MB); (256,6)->40 VGPR SPILL (R10).
__global__ __launch_bounds__(256) void enc_kernel(
    const float* __restrict__ rs, const float* __restrict__ ts,
    const float* __restrict__ r_w1, const float* __restrict__ r_b1,
    const float* __restrict__ r_w2, const float* __restrict__ r_b2,
    const float* __restrict__ t_w1, const float* __restrict__ t_b1,
    const float* __restrict__ t_w2, const float* __restrict__ t_b2,
    const float* __restrict__ wq, const float* __restrict__ bq,
    const float* __restrict__ wk, const float* __restrict__ bk,
    const float* __restrict__ wv, const float* __restrict__ bv,
    const float* __restrict__ a_w1, const float* __restrict__ a_w2,
    float* __restrict__ kbuf, float* __restrict__ vbuf,
    float* __restrict__ rpbuf, float* __restrict__ qbuf,
    unsigned short* __restrict__ w2f)
{
  __shared__ float w1s[448];
  __shared__ float wss[4096];
  __shared__ float h_s[32 * 66];
  __shared__ float rf_s[32 * 66];

  const int tid = threadIdx.x;
  const int blk = blockIdx.x;

  if (blk == 640) {        // fused prep: split a_w2 into hi/lo bf16 B-frags
    if (tid < 64) {
      int l = tid, n16 = l & 15, g = l >> 4;
      for (int f = 0; f < 8; ++f) {
        int ntile = f & 1, ks = (f >> 1) & 1, part = f >> 2;
        for (int j = 0; j < 8; ++j) {
          int k = ks * 32 + g * 8 + j;
          int n = ntile * 16 + n16;
          unsigned wb = __float_as_uint(a_w2[k * 32 + n]);
          unsigned hib = wb & 0xffff0000u;
          float lof = __uint_as_float(wb) - __uint_as_float(hib);
          unsigned lob = __float_as_uint(lof) & 0xffff0000u;
          w2f[((size_t)f * 64 + l) * 8 + j] =
              (unsigned short)((part == 0 ? hib : lob) >> 16);
        }
      }
    }
    return;
  }

  const int rb = tid >> 3, t8 = tid & 7;
  const bool robot = blk < 512;

  if (robot) {
    if (tid < 112) ((float4*)w1s)[tid] = ((const float4*)r_w1)[tid];
#pragma unroll
    for (int c = 0; c < 4; ++c)
      ((float4*)wss)[c * 256 + tid] = ((const float4*)r_w2)[c * 256 + tid];
  } else {
    if (tid < 96) ((float4*)w1s)[tid] = ((const float4*)t_w1)[tid];
#pragma unroll
    for (int c = 0; c < 4; ++c)
      ((float4*)wss)[c * 256 + tid] = ((const float4*)t_w2)[c * 256 + tid];
  }

  int g, K1;
  const float* xin; const float* b1; const float* b2;
  if (robot) { g = blk * 32 + rb;          K1 = 7; xin = rs + (size_t)g * 7; b1 = r_b1; b2 = r_b2; }
  else       { g = (blk - 512) * 32 + rb;  K1 = 6; xin = ts + (size_t)g * 6; b1 = t_b1; b2 = t_b2; }

  float x[7];
  for (int k = 0; k < K1; ++k) x[k] = xin[k];
  __syncthreads();

  // stage 1: hidden = relu(x @ W1 + b1)
  {
    float acc[8];
#pragma unroll
    for (int jj = 0; jj < 8; ++jj) acc[jj] = b1[t8 * 8 + jj];
    for (int k = 0; k < K1; ++k) {
      float xv = x[k];
#pragma unroll
      for (int jj = 0; jj < 8; ++jj) acc[jj] += xv * w1s[k * 64 + t8 * 8 + jj];
    }
#pragma unroll
    for (int jj = 0; jj < 8; ++jj) h_s[rb * 66 + t8 * 8 + jj] = fmaxf(acc[jj], 0.f);
  }
  __syncthreads();

  // stage 2: rf = relu(hidden @ W2 + b2)
  {
    float acc[8];
#pragma unroll
    for (int jj = 0; jj < 8; ++jj) acc[jj] = b2[t8 * 8 + jj];
    for (int k = 0; k < 64; ++k) {
      float hv = h_s[rb * 66 + k];
      const float4* wr = (const float4*)(wss + k * 64 + t8 * 8);
#pragma unroll
      for (int j4 = 0; j4 < 2; ++j4) {
        float4 w = wr[j4];
        acc[j4 * 4 + 0] += hv * w.x; acc[j4 * 4 + 1] += hv * w.y;
        acc[j4 * 4 + 2] += hv * w.z; acc[j4 * 4 + 3] += hv * w.w;
      }
    }
#pragma unroll
    for (int jj = 0; jj < 8; ++jj) rf_s[rb * 66 + t8 * 8 + jj] = fmaxf(acc[jj], 0.f);
  }

  // stage 3: projection passes
  const float* wp[3]; const float* bp[3]; float* op[3]; int npass;
  if (robot) {
    wp[0] = wk; bp[0] = bk;      op[0] = kbuf;
    wp[1] = wv; bp[1] = bv;      op[1] = vbuf;
    wp[2] = a_w1 + 64 * 64; bp[2] = nullptr; op[2] = rpbuf;
    npass = 3;
  } else {
    wp[0] = wq; bp[0] = bq; op[0] = qbuf; npass = 1;
  }
  for (int p = 0; p < npass; ++p) {
    __syncthreads();
#pragma unroll
    for (int c = 0; c < 4; ++c)
      ((float4*)wss)[c * 256 + tid] = ((const float4*)wp[p])[c * 256 + tid];
    __syncthreads();
    float acc[8];
#pragma unroll
    for (int jj = 0; jj < 8; ++jj) acc[jj] = bp[p] ? bp[p][t8 * 8 + jj] : 0.f;
    for (int k = 0; k < 64; ++k) {
      float hv = rf_s[rb * 66 + k];
      const float4* wr = (const float4*)(wss + k * 64 + t8 * 8);
#pragma unroll
      for (int j4 = 0; j4 < 2; ++j4) {
        float4 w = wr[j4];
        acc[j4 * 4 + 0] += hv * w.x; acc[j4 * 4 + 1] += hv * w.y;
        acc[j4 * 4 + 2] += hv * w.z; acc[j4 * 4 + 3] += hv * w.w;
      }
    }
    float4* o4 = (float4*)(op[p] + (size_t)g * 64 + t8 * 8);
    o4[0] = make_float4(acc[0], acc[1], acc[2], acc[3]);
    o4[1] = make_float4(acc[4], acc[5], acc[6], acc[7]);
  }
}

// ---------------- split helpers (pair) -------------------------------------
__device__ __forceinline__ void mk2(f32x2 r, f32x2 t,
                                    unsigned* h, unsigned* l)
{
  f32x2 x = r + t;                                     // v_pk_add_f32
  x = __builtin_elementwise_max(x, (f32x2){0.f, 0.f}); // v_pk_max_f32
  __hip_bfloat162 hb = __float22bfloat162_rn(make_float2(x.x, x.y));
  unsigned hh; __builtin_memcpy(&hh, &hb, 4);
  f32x2 hf;
  hf.x = __int_as_float((int)(hh << 16));
  hf.y = __int_as_float((int)(hh & 0xffff0000u));
  f32x2 e = x - hf;                                    // exact residual
  __hip_bfloat162 lb = __float22bfloat162_rn(make_float2(e.x, e.y));
  unsigned ll; __builtin_memcpy(&ll, &lb, 4);
  *h = hh; *l = ll;
}

__device__ __forceinline__ void mk_frags(float4 ra, float4 rb,
                                         float4 ta, float4 tb,
                                         short8* Ah, short8* Al)
{
  unsigned h0, h1, h2, h3, l0, l1, l2, l3;
  mk2((f32x2){ra.x, ra.y}, (f32x2){ta.x, ta.y}, &h0, &l0);
  mk2((f32x2){ra.z, ra.w}, (f32x2){ta.z, ta.w}, &h1, &l1);
  mk2((f32x2){rb.x, rb.y}, (f32x2){tb.x, tb.y}, &h2, &l2);
  mk2((f32x2){rb.z, rb.w}, (f32x2){tb.z, tb.w}, &h3, &l3);
  *Ah = __builtin_bit_cast(short8, make_int4((int)h0, (int)h1, (int)h2, (int)h3));
  *Al = __builtin_bit_cast(short8, make_int4((int)l0, (int)l1, (int)l2, (int)l3));
}

// ---------------- fused attention + pairwise kernel (R12 exact) ------------
// launch_bounds(256,4): VGPR 64, NO spill; scores unioned into lg ->
// LDS 20.4 KB. DO NOT raise min-waves: (256,5)+ clamps VGPR below the
// body's live range and spills to scratch (R10/R13: FETCH 9->100+ MB).
#define LGS 520
__global__ __launch_bounds__(256, 4) void attn_pair_kernel(
    const float* __restrict__ qbuf, const float* __restrict__ kbuf,
    const float* __restrict__ vbuf,
    const float* __restrict__ wo, const float* __restrict__ bo,
    const float* __restrict__ a_w1, const float* __restrict__ a_b1,
    const unsigned short* __restrict__ w2f,
    const float* __restrict__ a_b2, const float* __restrict__ a_w3,
    const float* __restrict__ rpbuf,
    float* __restrict__ out)
{
  __shared__ float qt_s[2 * 64];        // q in phase A, tf in phase D
  __shared__ float lg[2][4 * LGS];      // logits/probs; reused for scores
  __shared__ float inv_s[8];
  __shared__ float cp[4][2 * 64];
  __shared__ float ctx_s[2 * 64];
  __shared__ float tp_f[2 * 64];
  __shared__ float red_a[4];
  __shared__ float red_b[4];

  float* const sc0 = &lg[0][0];         // scores task 0 (aliases lg, dead)
  float* const sc1 = &lg[1][0];         // scores task 1

  const int tid = threadIdx.x;
  const int jj = blockIdx.x & 31;
  const int b  = (jj & 7) * 4 + (jj >> 3);   // XCD-locality swizzle
  const int t0 = (blockIdx.x >> 5) * 2;      // 64 task-pairs

  // ---------- attn phase A: logits ----------
  if (tid < 32) {
    int tt = tid >> 4, i4 = tid & 15;
    float4 v = ((const float4*)(qbuf + (size_t)(b * NT + t0 + tt) * 64))[i4];
    v.x *= 0.25f; v.y *= 0.25f; v.z *= 0.25f; v.w *= 0.25f;   // 1/sqrt(16)
    ((float4*)qt_s)[tid] = v;
  }
  __syncthreads();

  {
    const int h = tid & 3;
    const int r0 = tid >> 2;
    const float4* q0 = (const float4*)(qt_s + h * 16);
    const float4* q1 = (const float4*)(qt_s + 64 + h * 16);
    float4 q0a = q0[0], q0b = q0[1], q0c = q0[2], q0d = q0[3];
    float4 q1a = q1[0], q1b = q1[1], q1c = q1[2], q1d = q1[3];
    const float* kb0 = kbuf + (size_t)b * NR * 64 + h * 16;
    for (int it = 0; it < 8; ++it) {
      int r = r0 + it * 64;
      const float4* k4 = (const float4*)(kb0 + (size_t)r * 64);
      float4 ka = k4[0], kb = k4[1], kc = k4[2], kd = k4[3];
      float s0 = dot4(q0a, ka) + dot4(q0b, kb) + dot4(q0c, kc) + dot4(q0d, kd);
      float s1 = dot4(q1a, ka) + dot4(q1b, kb) + dot4(q1c, kc) + dot4(q1d, kd);
      lg[0][h * LGS + r] = s0;
      lg[1][h * LGS + r] = s1;
    }
  }
  __syncthreads();

  // ---------- attn phase B: softmax ----------
  {
    int w = tid >> 6, lane = tid & 63;
    for (int p = 0; p < 2; ++p) {
      int pr = w * 2 + p, tt = pr >> 2, hh = pr & 3;
      float* row = &lg[tt][hh * LGS];
      float v0[8];
#pragma unroll
      for (int u = 0; u < 8; ++u) v0[u] = row[u * 64 + lane];
      float m = v0[0];
#pragma unroll
      for (int u = 1; u < 8; ++u) m = fmaxf(m, v0[u]);
      m = wred_max(m);
      float s = 0.f;
#pragma unroll
      for (int u = 0; u < 8; ++u) {
        float e = expf(v0[u] - m);
        row[u * 64 + lane] = e;
        s += e;
      }
      s = wred_sum(s);
      if (lane == 0) inv_s[tt * 4 + hh] = 1.f / s;
    }
  }
  __syncthreads();

  // ---------- attn phase C: ctx = p.v ----------
  {
    int od = tid & 63, ch = tid >> 6;
    int h = od >> 4, d = od & 15;
    float acc0 = 0.f, acc1 = 0.f;
    const float* vptr = vbuf + (size_t)b * NR * 64 + h * 16 + d;
#pragma unroll 4
    for (int u = 0; u < 128; ++u) {
      int r = ch * 128 + u;
      float vv = vptr[(size_t)r * 64];
      acc0 += lg[0][h * LGS + r] * vv;
      acc1 += lg[1][h * LGS + r] * vv;
    }
    cp[ch][od]      = acc0;
    cp[ch][64 + od] = acc1;
  }
  __syncthreads();
  if (tid < 128) {
    int od = tid & 63, h = od >> 4;
    ctx_s[tid] = (cp[0][tid] + cp[1][tid] + cp[2][tid] + cp[3][tid]) *
                 inv_s[(tid >> 6) * 4 + h];
  }
  __syncthreads();

  // ---------- attn phase D: tf = ctx @ wo + bo ----------
  {
    int jd = tid & 63, kc = tid >> 6;
    float p0 = 0.f, p1 = 0.f;
    for (int k = 0; k < 16; ++k) {
      float w = wo[(kc * 16 + k) * 64 + jd];
      p0 += ctx_s[kc * 16 + k] * w;
      p1 += ctx_s[64 + kc * 16 + k] * w;
    }
    cp[kc][jd]      = p0;
    cp[kc][64 + jd] = p1;
  }
  __syncthreads();
  if (tid < 128) {
    int jd = tid & 63;
    qt_s[tid] = cp[0][tid] + cp[1][tid] + cp[2][tid] + cp[3][tid] + bo[jd];
  }
  __syncthreads();

  // ---------- attn phase E: tp = tf @ a_w1[:64] + a_b1 -> LDS ----------
  {
    int jd = tid & 63, kc = tid >> 6;
    float p0 = 0.f, p1 = 0.f;
    for (int k = 0; k < 16; ++k) {
      float w = a_w1[(kc * 16 + k) * 64 + jd];
      p0 += qt_s[kc * 16 + k] * w;
      p1 += qt_s[64 + kc * 16 + k] * w;
    }
    cp[kc][jd]      = p0;
    cp[kc][64 + jd] = p1;
  }
  __syncthreads();
  if (tid < 128) {
    int jd = tid & 63;
    tp_f[tid] = cp[0][tid] + cp[1][tid] + cp[2][tid] + cp[3][tid] + a_b1[jd];
  }
  __syncthreads();

  // ---------- pair body ----------
  const int wave = tid >> 6, lane = tid & 63;
  const int n16 = lane & 15, g = lane >> 4;

  short8 B[8];
#pragma unroll
  for (int f = 0; f < 8; ++f)
    B[f] = __builtin_bit_cast(short8, ((const int4*)w2f)[f * 64 + lane]);

  const float* tpA = tp_f + g * 8;
  const float* tpB = tp_f + 64 + g * 8;
  float4 tA0a = *(const float4*)(tpA),      tA0b = *(const float4*)(tpA + 4);
  float4 tA1a = *(const float4*)(tpA + 32), tA1b = *(const float4*)(tpA + 36);
  float4 tB0a = *(const float4*)(tpB),      tB0b = *(const float4*)(tpB + 4);
  float4 tB1a = *(const float4*)(tpB + 32), tB1b = *(const float4*)(tpB + 36);

  float b20 = a_b2[n16], b21 = a_b2[16 + n16];
  float w30 = a_w3[n16], w31 = a_w3[16 + n16];

  const float* rpb = rpbuf + (size_t)b * NR * 64 + g * 8;

  const float4* rp0 = (const float4*)(rpb + (size_t)(wave * 128 + n16) * 64);
  float4 ra0 = rp0[0], rb0 = rp0[1], ra1 = rp0[8], rb1 = rp0[9];

#pragma unroll
  for (int mt = 0; mt < 8; ++mt) {
    float4 na0, nb0, na1, nb1;
    if (mt < 7) {
      const float4* rpn =
          (const float4*)(rpb + (size_t)(wave * 128 + (mt + 1) * 16 + n16) * 64);
      na0 = rpn[0]; nb0 = rpn[1]; na1 = rpn[8]; nb1 = rpn[9];
    }

#pragma unroll
    for (int task = 0; task < 2; ++task) {
      short8 Ah0, Al0, Ah1, Al1;
      if (task == 0) {
        mk_frags(ra0, rb0, tA0a, tA0b, &Ah0, &Al0);
        mk_frags(ra1, rb1, tA1a, tA1b, &Ah1, &Al1);
      } else {
        mk_frags(ra0, rb0, tB0a, tB0b, &Ah0, &Al0);
        mk_frags(ra1, rb1, tB1a, tB1b, &Ah1, &Al1);
      }
      f32x4 acc0 = (f32x4){b20, b20, b20, b20};
      f32x4 acc1 = (f32x4){b21, b21, b21, b21};
      acc0 = __builtin_amdgcn_mfma_f32_16x16x32_bf16(Ah0, B[0], acc0, 0, 0, 0);
      acc1 = __builtin_amdgcn_mfma_f32_16x16x32_bf16(Ah0, B[1], acc1, 0, 0, 0);
      acc0 = __builtin_amdgcn_mfma_f32_16x16x32_bf16(Al0, B[0], acc0, 0, 0, 0);
      acc1 = __builtin_amdgcn_mfma_f32_16x16x32_bf16(Al0, B[1], acc1, 0, 0, 0);
      acc0 = __builtin_amdgcn_mfma_f32_16x16x32_bf16(Ah0, B[4], acc0, 0, 0, 0);
      acc1 = __builtin_amdgcn_mfma_f32_16x16x32_bf16(Ah0, B[5], acc1, 0, 0, 0);
      acc0 = __builtin_amdgcn_mfma_f32_16x16x32_bf16(Ah1, B[2], acc0, 0, 0, 0);
      acc1 = __builtin_amdgcn_mfma_f32_16x16x32_bf16(Ah1, B[3], acc1, 0, 0, 0);
      acc0 = __builtin_amdgcn_mfma_f32_16x16x32_bf16(Al1, B[2], acc0, 0, 0, 0);
      acc1 = __builtin_amdgcn_mfma_f32_16x16x32_bf16(Al1, B[3], acc1, 0, 0, 0);
      acc0 = __builtin_amdgcn_mfma_f32_16x16x32_bf16(Ah1, B[6], acc0, 0, 0, 0);
      acc1 = __builtin_amdgcn_mfma_f32_16x16x32_bf16(Ah1, B[7], acc1, 0, 0, 0);
#pragma unroll
      for (int reg = 0; reg < 4; ++reg) {
        float s = fmaxf(acc0[reg], 0.f) * w30 + fmaxf(acc1[reg], 0.f) * w31;
        s = dpp_add16(s);                 // VALU-only 16-lane reduction
        if (n16 == 15) {
          float* scp = (task == 0) ? sc0 : sc1;
          scp[wave * 128 + mt * 16 + g * 4 + reg] = s;
        }
      }
    }
    ra0 = na0; rb0 = nb0; ra1 = na1; rb1 = nb1;
  }
  __syncthreads();

  // ---------- softmax over 512 robots, 2 tasks ----------
  const int lw = tid & 63, wid = tid >> 6;
  for (int task = 0; task < 2; ++task) {
    const float* scp = (task == 0) ? sc0 : sc1;
    float s0 = scp[tid], s1 = scp[tid + 256];
    float mw = wred_max(fmaxf(s0, s1));
    if (lw == 0) red_a[wid] = mw;
    __syncthreads();
    float m = fmaxf(fmaxf(red_a[0], red_a[1]), fmaxf(red_a[2], red_a[3]));
    float e0 = expf(s0 - m), e1 = expf(s1 - m);
    float sw = wred_sum(e0 + e1);
    if (lw == 0) red_b[wid] = sw;
    __syncthreads();
    float inv = 1.f / (red_b[0] + red_b[1] + red_b[2] + red_b[3]);
    float* op = out + (size_t)(b * NT + t0 + task) * NR;
    op[tid]       = e0 * inv;
    op[256 + tid] = e1 * inv;
  }
}

// ---------------- launch ----------------
extern "C" void kernel_launch(void* const* d_in, const int* in_sizes, int n_in,
                              void* d_out, int out_size, void* d_ws, size_t ws_size,
                              hipStream_t stream)
{
  const float* rs   = (const float*)d_in[0];
  const float* ts   = (const float*)d_in[1];
  const float* r_w1 = (const float*)d_in[2];  const float* r_b1 = (const float*)d_in[3];
  const float* r_w2 = (const float*)d_in[4];  const float* r_b2 = (const float*)d_in[5];
  const float* t_w1 = (const float*)d_in[6];  const float* t_b1 = (const float*)d_in[7];
  const float* t_w2 = (const float*)d_in[8];  const float* t_b2 = (const float*)d_in[9];
  const float* wq   = (const float*)d_in[10]; const float* bq   = (const float*)d_in[11];
  const float* wk   = (const float*)d_in[12]; const float* bk   = (const float*)d_in[13];
  const float* wv   = (const float*)d_in[14]; const float* bv   = (const float*)d_in[15];
  const float* wo   = (const float*)d_in[16]; const float* bo   = (const float*)d_in[17];
  const float* a_w1 = (const float*)d_in[18]; const float* a_b1 = (const float*)d_in[19];
  const float* a_w2 = (const float*)d_in[20]; const float* a_b2 = (const float*)d_in[21];
  const float* a_w3 = (const float*)d_in[22]; const float* a_b3 = (const float*)d_in[23];

  float* wsf   = (float*)d_ws;
  float* kbuf  = wsf;                                   // 32*512*64
  float* vbuf  = kbuf  + (size_t)NB * NR * 64;          // 32*512*64
  float* rpbuf = vbuf  + (size_t)NB * NR * 64;          // 32*512*64
  float* qbuf  = rpbuf + (size_t)NB * NR * 64;          // 32*128*64
  unsigned short* w2f = (unsigned short*)(qbuf + (size_t)NB * NT * 64); // 8*64*8

  enc_kernel<<<dim3(641), dim3(256), 0, stream>>>(
      rs, ts, r_w1, r_b1, r_w2, r_b2, t_w1, t_b1, t_w2, t_b2,
      wq, bq, wk, bk, wv, bv, a_w1, a_w2, kbuf, vbuf, rpbuf, qbuf, w2f);

  attn_pair_kernel<<<dim3(2048), dim3(256), 0, stream>>>(
      qbuf, kbuf, vbuf, wo, bo, a_w1, a_b1, w2f, a_b2, a_w3, rpbuf,
      (float*)d_out);
}